// Round 1
// baseline (716.988 us; speedup 1.0000x reference)
//
#include <hip/hip_runtime.h>

typedef _Float16 f16x8 __attribute__((ext_vector_type(8)));
typedef float f32x4 __attribute__((ext_vector_type(4)));

__device__ __forceinline__ void gload16(const void* g, void* l) {
  __builtin_amdgcn_global_load_lds(
      (const __attribute__((address_space(1))) void*)g,
      (__attribute__((address_space(3))) void*)l, 16, 0, 0);
}

// m204 bijective XCD swizzle: contiguous logical range per XCD
__device__ __forceinline__ int xcd_swz(int orig, int nwg) {
  int q = nwg >> 3, r = nwg & 7;
  int x = orig & 7, loc = orig >> 3;
  int base = (x < r) ? x * (q + 1) : r * (q + 1) + (x - r) * q;
  return base + loc;
}

// ---------------- weight transpose + cast: W (KxN f32) -> WT (NxK f16) -------
__global__ __launch_bounds__(256) void transpose_w(const float* __restrict__ W,
                                                   _Float16* __restrict__ WT, int K) {
  const int N = 1024;
  __shared__ float tile[32][33];
  int tx = threadIdx.x, ty = threadIdx.y;  // (32,8)
  int n0 = blockIdx.x * 32, k0 = blockIdx.y * 32;
#pragma unroll
  for (int i = 0; i < 4; i++)
    tile[ty + i * 8][tx] = W[(long)(k0 + ty + i * 8) * N + (n0 + tx)];
  __syncthreads();
#pragma unroll
  for (int i = 0; i < 4; i++)
    WT[(long)(n0 + ty + i * 8) * K + (k0 + tx)] = (_Float16)tile[tx][ty + i * 8];
}

// ---------------- plain rows: f32 -> f16 cast ---------------------------------
__global__ __launch_bounds__(256) void cast_f16(const float* __restrict__ in,
                                                _Float16* __restrict__ out, long n) {
  long i = ((long)blockIdx.x * 256 + threadIdx.x) * 4;
  if (i < n) {
    float4 v = *(const float4*)(in + i);
    _Float16 o0 = (_Float16)v.x, o1 = (_Float16)v.y, o2 = (_Float16)v.z, o3 = (_Float16)v.w;
    // 8B vector store
    typedef _Float16 f16x4 __attribute__((ext_vector_type(4)));
    f16x4 o = {o0, o1, o2, o3};
    *(f16x4*)(out + i) = o;
  }
}

// ---------------- exact per-row top-k corruption ------------------------------
// One block = one x-row. Bitonic sort 512 value-bits descending, then
// threshold+tie-rank (lower index first, matching jax.lax.top_k).
__global__ __launch_bounds__(256) void topk_corrupt(
    const float* __restrict__ noise, const float* __restrict__ x,
    const float* __restrict__ u, const float* __restrict__ mmin,
    const float* __restrict__ mmax, const int* __restrict__ kptr,
    _Float16* __restrict__ dst, int xrow0) {
  __shared__ unsigned sv[512];
  __shared__ float vals[512];
  __shared__ unsigned sh_t;
  __shared__ int sh_cgt;
  int t = threadIdx.x;
  long row = (long)xrow0 + blockIdx.x;
  const float* nr = noise + row * 512;
  float v0 = nr[t], v1 = nr[t + 256];
  vals[t] = v0; vals[t + 256] = v1;
  sv[t] = __float_as_uint(v0);          // uniform [0,1): bits are order-monotone
  sv[t + 256] = __float_as_uint(v1);
  __syncthreads();
  for (int k = 2; k <= 512; k <<= 1) {
    for (int j = k >> 1; j > 0; j >>= 1) {
#pragma unroll
      for (int e = 0; e < 2; e++) {
        int i = t + e * 256;
        int ix = i ^ j;
        if (ix > i) {
          unsigned a = sv[i], b = sv[ix];
          bool up = ((i & k) == 0);           // descending overall
          if (up ? (a < b) : (a > b)) { sv[i] = b; sv[ix] = a; }
        }
      }
      __syncthreads();
    }
  }
  int kk = *kptr;  // 307
  if (t == 0) sh_t = sv[kk - 1];
  __syncthreads();
  unsigned tv = sh_t;
#pragma unroll
  for (int e = 0; e < 2; e++) {
    int i = t + e * 256;
    if (sv[i] == tv && (i == 0 || sv[i - 1] != tv)) sh_cgt = i;  // first occurrence = #strictly-greater
  }
  __syncthreads();
  int need = kk - sh_cgt;  // how many tied values to take (lowest indices)
  const float* xr = x + row * 512;
  const float* ur = u + row * 512;
  _Float16* dr = dst + (long)blockIdx.x * 512;
#pragma unroll
  for (int e = 0; e < 2; e++) {
    int j = t + e * 256;
    unsigned b = __float_as_uint(vals[j]);
    bool m;
    if (b > tv) m = true;
    else if (b != tv) m = false;
    else {  // rare tie at the boundary: rank among equal values by ascending index
      int rk = 0;
      for (int q = 0; q < j; q++) rk += (__float_as_uint(vals[q]) == tv) ? 1 : 0;
      m = (rk < need);
    }
    float val = m ? (mmin[j] + ur[j] * (mmax[j] - mmin[j])) : xr[j];
    dr[j] = (_Float16)val;
  }
}

// ---------------- f16 GEMM, m97 structure: 128x128 tile, BK=32 ---------------
// A: MxK row-major f16 (M multiple of 128). BT: NxK row-major f16 (N=1024).
// C = A*B + bias [, relu]; OUTF32 ? f32 : f16 output, row-major MxN.
template <bool RELU, bool OUTF32>
__global__ __launch_bounds__(256) void gemm_bt(const _Float16* __restrict__ A,
                                               const _Float16* __restrict__ BT,
                                               const float* __restrict__ bias,
                                               void* __restrict__ Cout, int K) {
  const int N = 1024;
  __shared__ _Float16 As[128 * 32];  // [m][k], 64B rows
  __shared__ _Float16 Bs[128 * 32];  // [n][k]
  int tid = threadIdx.x;
  int lane = tid & 63, wave = tid >> 6;
  int logical = xcd_swz(blockIdx.x, gridDim.x);
  int bn = logical & 7;            // fast axis: 8 blocks share one A panel
  long arow0 = (long)(logical >> 3) * 128;
  int bcol0 = bn * 128;
  int wm = (wave >> 1) * 64, wn = (wave & 1) * 64;

  int sr = tid >> 2;           // staging row 0..63
  int si = (tid & 3) * 8;      // element offset in 32-elem row (16B chunks)
  const _Float16* Ag0 = A + (arow0 + sr) * (long)K + si;
  const _Float16* Ag1 = A + (arow0 + 64 + sr) * (long)K + si;
  const _Float16* Bg0 = BT + (long)(bcol0 + sr) * K + si;
  const _Float16* Bg1 = BT + (long)(bcol0 + 64 + sr) * K + si;
  _Float16* Al0 = &As[sr * 32 + si];
  _Float16* Al1 = &As[(64 + sr) * 32 + si];
  _Float16* Bl0 = &Bs[sr * 32 + si];
  _Float16* Bl1 = &Bs[(64 + sr) * 32 + si];

  f32x4 acc[4][4] = {};
  int lr = lane & 15;
  int lk = (lane >> 4) * 8;

  for (int kt = 0; kt < K; kt += 32) {
    __syncthreads();                     // LDS reads of prev tile done
    gload16(Ag0 + kt, Al0);
    gload16(Ag1 + kt, Al1);
    gload16(Bg0 + kt, Bl0);
    gload16(Bg1 + kt, Bl1);
    __syncthreads();                     // compiler drains vmcnt before barrier
    f16x8 af[4], bfg[4];
#pragma unroll
    for (int m = 0; m < 4; m++) af[m] = *(const f16x8*)&As[(wm + m * 16 + lr) * 32 + lk];
#pragma unroll
    for (int n = 0; n < 4; n++) bfg[n] = *(const f16x8*)&Bs[(wn + n * 16 + lr) * 32 + lk];
#pragma unroll
    for (int m = 0; m < 4; m++)
#pragma unroll
      for (int n = 0; n < 4; n++)
        acc[m][n] = __builtin_amdgcn_mfma_f32_16x16x32_f16(af[m], bfg[n], acc[m][n], 0, 0, 0);
  }

  // epilogue: C/D layout col=lane&15, row=(lane>>4)*4+reg  [m89]
  int r0 = (lane >> 4) * 4;
  float bv[4];
#pragma unroll
  for (int n = 0; n < 4; n++) bv[n] = bias[bcol0 + wn + n * 16 + lr];
#pragma unroll
  for (int m = 0; m < 4; m++) {
    long rowb = arow0 + wm + m * 16 + r0;
#pragma unroll
    for (int n = 0; n < 4; n++) {
      int col = bcol0 + wn + n * 16 + lr;
#pragma unroll
      for (int r = 0; r < 4; r++) {
        float v = acc[m][n][r] + bv[n];
        if (RELU) v = fmaxf(v, 0.f);
        if (OUTF32) ((float*)Cout)[(rowb + r) * N + col] = v;
        else ((_Float16*)Cout)[(rowb + r) * N + col] = (_Float16)v;
      }
    }
  }
}

extern "C" void kernel_launch(void* const* d_in, const int* in_sizes, int n_in,
                              void* d_out, int out_size, void* d_ws, size_t ws_size,
                              hipStream_t stream) {
  const float* x    = (const float*)d_in[0];
  const float* rn   = (const float*)d_in[1];
  const float* ur   = (const float*)d_in[2];
  const float* mmin = (const float*)d_in[3];
  const float* mmax = (const float*)d_in[4];
  const float* W[6]  = {(const float*)d_in[5],  (const float*)d_in[7],  (const float*)d_in[9],
                        (const float*)d_in[11], (const float*)d_in[13], (const float*)d_in[15]};
  const float* Bi[6] = {(const float*)d_in[6],  (const float*)d_in[8],  (const float*)d_in[10],
                        (const float*)d_in[12], (const float*)d_in[14], (const float*)d_in[16]};
  const int* kptr = (const int*)d_in[17];
  float* out = (float*)d_out;

  const long B = 16384;
  const int E = 1024;
  const int Ks[6] = {512, 1024, 1024, 1024, 1024, 1024};

  // ws layout: [wT0..wT5][both_chunk][h0][h1]
  char* ws = (char*)d_ws;
  _Float16* wT[6];
  size_t off = 0;
  for (int i = 0; i < 6; i++) { wT[i] = (_Float16*)(ws + off); off += (size_t)Ks[i] * E * 2; }
  size_t rem = (ws_size > off) ? ws_size - off : 0;
  long R = 32768;
  while (R > 128 && (size_t)R * 5120 > rem) R >>= 1;   // both(1024R)+2*h(4096R) bytes

  _Float16* bothc = (_Float16*)(ws + off);
  _Float16* h0 = bothc + R * 512;
  _Float16* h1 = h0 + R * 1024;

  // one-time (per call) weight transposes
  for (int i = 0; i < 6; i++) {
    dim3 g(E / 32, Ks[i] / 32), b(32, 8);
    transpose_w<<<g, b, 0, stream>>>(W[i], wT[i], Ks[i]);
  }

  for (long r0 = 0; r0 < 2 * B; r0 += R) {
    // ---- build rows [r0, r0+R) of `both` in f16 ----
    long plainEnd = (r0 < B) ? ((r0 + R < B) ? (r0 + R) : B) : r0;
    long p1 = plainEnd - r0;
    if (p1 > 0) {
      long n = p1 * 512;
      long blocks = (n / 4 + 255) / 256;
      cast_f16<<<dim3((unsigned)blocks), dim3(256), 0, stream>>>(x + r0 * 512, bothc, n);
    }
    long c0 = (r0 > B) ? r0 : B;
    long p2 = (r0 + R) - c0;
    if (p2 > 0) {
      topk_corrupt<<<dim3((unsigned)p2), dim3(256), 0, stream>>>(
          rn, x, ur, mmin, mmax, kptr, bothc + (c0 - r0) * 512, (int)(c0 - B));
    }
    // ---- 6-layer MLP on this chunk ----
    dim3 gg((unsigned)((R / 128) * 8)), gb(256);
    gemm_bt<true,  false><<<gg, gb, 0, stream>>>(bothc, wT[0], Bi[0], (void*)h0, 512);
    gemm_bt<true,  false><<<gg, gb, 0, stream>>>(h0,    wT[1], Bi[1], (void*)h1, 1024);
    gemm_bt<true,  false><<<gg, gb, 0, stream>>>(h1,    wT[2], Bi[2], (void*)h0, 1024);
    gemm_bt<false, false><<<gg, gb, 0, stream>>>(h0,    wT[3], Bi[3], (void*)h1, 1024);
    gemm_bt<true,  false><<<gg, gb, 0, stream>>>(h1,    wT[4], Bi[4], (void*)h0, 1024);
    gemm_bt<false, true ><<<gg, gb, 0, stream>>>(h0,    wT[5], Bi[5],
                                                 (void*)(out + r0 * 1024), 1024);
  }
}

// Round 2
// 573.579 us; speedup vs baseline: 1.2500x; 1.2500x over previous
//
#include <hip/hip_runtime.h>

typedef _Float16 f16x8 __attribute__((ext_vector_type(8)));
typedef float f32x4 __attribute__((ext_vector_type(4)));

__device__ __forceinline__ void gload16(const void* g, void* l) {
  __builtin_amdgcn_global_load_lds(
      (const __attribute__((address_space(1))) void*)g,
      (__attribute__((address_space(3))) void*)l, 16, 0, 0);
}

// m204 bijective XCD swizzle: contiguous logical range per XCD
__device__ __forceinline__ int xcd_swz(int orig, int nwg) {
  int q = nwg >> 3, r = nwg & 7;
  int x = orig & 7, loc = orig >> 3;
  int base = (x < r) ? x * (q + 1) : r * (q + 1) + (x - r) * q;
  return base + loc;
}

// ---------------- weight transpose + cast: W (KxN f32) -> WT (NxK f16) -------
__global__ __launch_bounds__(256) void transpose_w(const float* __restrict__ W,
                                                   _Float16* __restrict__ WT, int K) {
  const int N = 1024;
  __shared__ float tile[32][33];
  int tx = threadIdx.x, ty = threadIdx.y;  // (32,8)
  int n0 = blockIdx.x * 32, k0 = blockIdx.y * 32;
#pragma unroll
  for (int i = 0; i < 4; i++)
    tile[ty + i * 8][tx] = W[(long)(k0 + ty + i * 8) * N + (n0 + tx)];
  __syncthreads();
#pragma unroll
  for (int i = 0; i < 4; i++)
    WT[(long)(n0 + ty + i * 8) * K + (k0 + tx)] = (_Float16)tile[tx][ty + i * 8];
}

// ---------------- plain rows: f32 -> f16 cast (fallback path only) -----------
__global__ __launch_bounds__(256) void cast_f16(const float* __restrict__ in,
                                                _Float16* __restrict__ out, long n) {
  long i = ((long)blockIdx.x * 256 + threadIdx.x) * 4;
  if (i < n) {
    float4 v = *(const float4*)(in + i);
    typedef _Float16 f16x4 __attribute__((ext_vector_type(4)));
    f16x4 o = {(_Float16)v.x, (_Float16)v.y, (_Float16)v.z, (_Float16)v.w};
    *(f16x4*)(out + i) = o;
  }
}

// ---------------- exact per-row top-k corruption, 1 wave per row -------------
// Binary radix search on float bits (all values >= 0, bits order-monotone).
// Counts via __ballot -> SGPR popcount; no LDS, no barriers.
// Tie-break: lowest index first (matches jax.lax.top_k).
// Writes corrupted f16 row; if dplain != null also writes plain f16 cast of x.
__global__ __launch_bounds__(256) void topk_corrupt(
    const float* __restrict__ noise, const float* __restrict__ x,
    const float* __restrict__ u, const float* __restrict__ mmin,
    const float* __restrict__ mmax, const int* __restrict__ kptr,
    _Float16* __restrict__ dplain, _Float16* __restrict__ dcorr,
    int xrow0, int nrows) {
  int lane = threadIdx.x & 63;
  int r = (blockIdx.x << 2) + (threadIdx.x >> 6);
  if (r >= nrows) return;
  long row = (long)xrow0 + r;
  long rb = row * 512 + lane * 8;
  float4 n0 = *(const float4*)(noise + rb);
  float4 n1 = *(const float4*)(noise + rb + 4);
  unsigned v[8] = {__float_as_uint(n0.x), __float_as_uint(n0.y),
                   __float_as_uint(n0.z), __float_as_uint(n0.w),
                   __float_as_uint(n1.x), __float_as_uint(n1.y),
                   __float_as_uint(n1.z), __float_as_uint(n1.w)};
  int kk = *kptr;
  // T = largest uint with count(v >= T) >= kk  ==> T is the kk-th largest value
  unsigned T = 0;
  for (int bit = 30; bit >= 0; --bit) {   // bit31 (sign) always 0 for these inputs
    unsigned Tp = T | (1u << bit);
    int c = 0;
#pragma unroll
    for (int j = 0; j < 8; j++) c += (int)__popcll(__ballot(v[j] >= Tp));
    if (c >= kk) T = Tp;
  }
  int cgt = 0;
  unsigned long long eqb[8];
#pragma unroll
  for (int j = 0; j < 8; j++) {
    cgt += (int)__popcll(__ballot(v[j] > T));
    eqb[j] = __ballot(v[j] == T);
  }
  int need = kk - cgt;  // # tied values to take, by ascending index
  unsigned long long below = (1ull << lane) - 1ull;  // lower-index lanes
  int rank_base = 0;    // equals in lower lanes (any j), since index = lane*8+j
#pragma unroll
  for (int j = 0; j < 8; j++) rank_base += (int)__popcll(eqb[j] & below);

  float4 x0 = *(const float4*)(x + rb);
  float4 x1 = *(const float4*)(x + rb + 4);
  float4 u0 = *(const float4*)(u + rb);
  float4 u1 = *(const float4*)(u + rb + 4);
  int col = lane * 8;
  float4 mn0 = *(const float4*)(mmin + col);
  float4 mn1 = *(const float4*)(mmin + col + 4);
  float4 mx0 = *(const float4*)(mmax + col);
  float4 mx1 = *(const float4*)(mmax + col + 4);
  float xs[8] = {x0.x, x0.y, x0.z, x0.w, x1.x, x1.y, x1.z, x1.w};
  float us[8] = {u0.x, u0.y, u0.z, u0.w, u1.x, u1.y, u1.z, u1.w};
  float mns[8] = {mn0.x, mn0.y, mn0.z, mn0.w, mn1.x, mn1.y, mn1.z, mn1.w};
  float mxs[8] = {mx0.x, mx0.y, mx0.z, mx0.w, mx1.x, mx1.y, mx1.z, mx1.w};

  f16x8 po, co;
  int loc = 0;  // equals in same lane with smaller j
#pragma unroll
  for (int j = 0; j < 8; j++) {
    bool eq = (v[j] == T);
    int rank = rank_base + loc;
    bool m = (v[j] > T) || (eq && (rank < need));
    loc += eq ? 1 : 0;
    float rv = mns[j] + us[j] * (mxs[j] - mns[j]);
    float cv = m ? rv : xs[j];
    po[j] = (_Float16)xs[j];
    co[j] = (_Float16)cv;
  }
  long ob = (long)r * 512 + lane * 8;
  if (dplain) *(f16x8*)(dplain + ob) = po;
  *(f16x8*)(dcorr + ob) = co;
}

// ---------------- f16 GEMM, m97 structure: 128x128 tile, BK=32 ---------------
// A: MxK row-major f16 (M multiple of 128). BT: NxK row-major f16 (N=1024).
// C = A*B + bias [, relu]; OUTF32 ? f32 : f16 output, row-major MxN.
template <bool RELU, bool OUTF32>
__global__ __launch_bounds__(256) void gemm_bt(const _Float16* __restrict__ A,
                                               const _Float16* __restrict__ BT,
                                               const float* __restrict__ bias,
                                               void* __restrict__ Cout, int K) {
  const int N = 1024;
  __shared__ _Float16 As[128 * 32];  // [m][k], 64B rows
  __shared__ _Float16 Bs[128 * 32];  // [n][k]
  int tid = threadIdx.x;
  int lane = tid & 63, wave = tid >> 6;
  int logical = xcd_swz(blockIdx.x, gridDim.x);
  int bn = logical & 7;            // fast axis: 8 blocks share one A panel
  long arow0 = (long)(logical >> 3) * 128;
  int bcol0 = bn * 128;
  int wm = (wave >> 1) * 64, wn = (wave & 1) * 64;

  int sr = tid >> 2;           // staging row 0..63
  int si = (tid & 3) * 8;      // element offset in 32-elem row (16B chunks)
  const _Float16* Ag0 = A + (arow0 + sr) * (long)K + si;
  const _Float16* Ag1 = A + (arow0 + 64 + sr) * (long)K + si;
  const _Float16* Bg0 = BT + (long)(bcol0 + sr) * K + si;
  const _Float16* Bg1 = BT + (long)(bcol0 + 64 + sr) * K + si;
  _Float16* Al0 = &As[sr * 32 + si];
  _Float16* Al1 = &As[(64 + sr) * 32 + si];
  _Float16* Bl0 = &Bs[sr * 32 + si];
  _Float16* Bl1 = &Bs[(64 + sr) * 32 + si];

  f32x4 acc[4][4] = {};
  int lr = lane & 15;
  int lk = (lane >> 4) * 8;

  for (int kt = 0; kt < K; kt += 32) {
    __syncthreads();                     // LDS reads of prev tile done
    gload16(Ag0 + kt, Al0);
    gload16(Ag1 + kt, Al1);
    gload16(Bg0 + kt, Bl0);
    gload16(Bg1 + kt, Bl1);
    __syncthreads();                     // compiler drains vmcnt before barrier
    f16x8 af[4], bfg[4];
#pragma unroll
    for (int m = 0; m < 4; m++) af[m] = *(const f16x8*)&As[(wm + m * 16 + lr) * 32 + lk];
#pragma unroll
    for (int n = 0; n < 4; n++) bfg[n] = *(const f16x8*)&Bs[(wn + n * 16 + lr) * 32 + lk];
#pragma unroll
    for (int m = 0; m < 4; m++)
#pragma unroll
      for (int n = 0; n < 4; n++)
        acc[m][n] = __builtin_amdgcn_mfma_f32_16x16x32_f16(af[m], bfg[n], acc[m][n], 0, 0, 0);
  }

  // epilogue: C/D layout col=lane&15, row=(lane>>4)*4+reg  [m89]
  int r0 = (lane >> 4) * 4;
  float bv[4];
#pragma unroll
  for (int n = 0; n < 4; n++) bv[n] = bias[bcol0 + wn + n * 16 + lr];
#pragma unroll
  for (int m = 0; m < 4; m++) {
    long rowb = arow0 + wm + m * 16 + r0;
#pragma unroll
    for (int n = 0; n < 4; n++) {
      int col = bcol0 + wn + n * 16 + lr;
#pragma unroll
      for (int r = 0; r < 4; r++) {
        float v = acc[m][n][r] + bv[n];
        if (RELU) v = fmaxf(v, 0.f);
        if (OUTF32) ((float*)Cout)[(rowb + r) * N + col] = v;
        else ((_Float16*)Cout)[(rowb + r) * N + col] = (_Float16)v;
      }
    }
  }
}

extern "C" void kernel_launch(void* const* d_in, const int* in_sizes, int n_in,
                              void* d_out, int out_size, void* d_ws, size_t ws_size,
                              hipStream_t stream) {
  const float* x    = (const float*)d_in[0];
  const float* rn   = (const float*)d_in[1];
  const float* ur   = (const float*)d_in[2];
  const float* mmin = (const float*)d_in[3];
  const float* mmax = (const float*)d_in[4];
  const float* W[6]  = {(const float*)d_in[5],  (const float*)d_in[7],  (const float*)d_in[9],
                        (const float*)d_in[11], (const float*)d_in[13], (const float*)d_in[15]};
  const float* Bi[6] = {(const float*)d_in[6],  (const float*)d_in[8],  (const float*)d_in[10],
                        (const float*)d_in[12], (const float*)d_in[14], (const float*)d_in[16]};
  const int* kptr = (const int*)d_in[17];
  float* out = (float*)d_out;

  const long B = 16384;
  const int E = 1024;
  const int Ks[6] = {512, 1024, 1024, 1024, 1024, 1024};

  // ws layout: [wT0..wT5][both_chunk][h0][h1]
  char* ws = (char*)d_ws;
  _Float16* wT[6];
  size_t off = 0;
  for (int i = 0; i < 6; i++) { wT[i] = (_Float16*)(ws + off); off += (size_t)Ks[i] * E * 2; }
  size_t rem = (ws_size > off) ? ws_size - off : 0;
  long R = 32768;
  while (R > 128 && (size_t)R * 5120 > rem) R >>= 1;   // both(1024R)+2*h(4096R) bytes

  _Float16* bothc = (_Float16*)(ws + off);
  _Float16* h0 = bothc + R * 512;
  _Float16* h1 = h0 + R * 1024;

  // one-time (per call) weight transposes
  for (int i = 0; i < 6; i++) {
    dim3 g(E / 32, Ks[i] / 32), b(32, 8);
    transpose_w<<<g, b, 0, stream>>>(W[i], wT[i], Ks[i]);
  }

  for (long r0 = 0; r0 < 2 * B; r0 += R) {
    // ---- build rows [r0, r0+R) of `both` in f16 ----
    if (R == 2 * B) {
      // fused: one kernel writes plain rows [0,B) and corrupted rows [B,2B)
      topk_corrupt<<<dim3((unsigned)(B / 4)), dim3(256), 0, stream>>>(
          rn, x, ur, mmin, mmax, kptr, bothc, bothc + B * 512, 0, (int)B);
    } else {
      long plainEnd = (r0 < B) ? ((r0 + R < B) ? (r0 + R) : B) : r0;
      long p1 = plainEnd - r0;
      if (p1 > 0) {
        long n = p1 * 512;
        long blocks = (n / 4 + 255) / 256;
        cast_f16<<<dim3((unsigned)blocks), dim3(256), 0, stream>>>(x + r0 * 512, bothc, n);
      }
      long c0 = (r0 > B) ? r0 : B;
      long p2 = (r0 + R) - c0;
      if (p2 > 0) {
        topk_corrupt<<<dim3((unsigned)((p2 + 3) / 4)), dim3(256), 0, stream>>>(
            rn, x, ur, mmin, mmax, kptr, (_Float16*)nullptr,
            bothc + (c0 - r0) * 512, (int)(c0 - B), (int)p2);
      }
    }
    // ---- 6-layer MLP on this chunk ----
    dim3 gg((unsigned)((R / 128) * 8)), gb(256);
    gemm_bt<true,  false><<<gg, gb, 0, stream>>>(bothc, wT[0], Bi[0], (void*)h0, 512);
    gemm_bt<true,  false><<<gg, gb, 0, stream>>>(h0,    wT[1], Bi[1], (void*)h1, 1024);
    gemm_bt<true,  false><<<gg, gb, 0, stream>>>(h1,    wT[2], Bi[2], (void*)h0, 1024);
    gemm_bt<false, false><<<gg, gb, 0, stream>>>(h0,    wT[3], Bi[3], (void*)h1, 1024);
    gemm_bt<true,  false><<<gg, gb, 0, stream>>>(h1,    wT[4], Bi[4], (void*)h0, 1024);
    gemm_bt<false, true ><<<gg, gb, 0, stream>>>(h0,    wT[5], Bi[5],
                                                 (void*)(out + r0 * 1024), 1024);
  }
}

// Round 3
// 560.472 us; speedup vs baseline: 1.2793x; 1.0234x over previous
//
#include <hip/hip_runtime.h>

typedef _Float16 f16x8 __attribute__((ext_vector_type(8)));
typedef float f32x4 __attribute__((ext_vector_type(4)));

__device__ __forceinline__ void gload16(const void* g, void* l) {
  __builtin_amdgcn_global_load_lds(
      (const __attribute__((address_space(1))) void*)g,
      (__attribute__((address_space(3))) void*)l, 16, 0, 0);
}

// m204 bijective XCD swizzle: contiguous logical range per XCD
__device__ __forceinline__ int xcd_swz(int orig, int nwg) {
  int q = nwg >> 3, r = nwg & 7;
  int x = orig & 7, loc = orig >> 3;
  int base = (x < r) ? x * (q + 1) : r * (q + 1) + (x - r) * q;
  return base + loc;
}

// ---------------- weight transpose + cast: W (KxN f32) -> WT (NxK f16) -------
__global__ __launch_bounds__(256) void transpose_w(const float* __restrict__ W,
                                                   _Float16* __restrict__ WT, int K) {
  const int N = 1024;
  __shared__ float tile[32][33];
  int tx = threadIdx.x, ty = threadIdx.y;  // (32,8)
  int n0 = blockIdx.x * 32, k0 = blockIdx.y * 32;
#pragma unroll
  for (int i = 0; i < 4; i++)
    tile[ty + i * 8][tx] = W[(long)(k0 + ty + i * 8) * N + (n0 + tx)];
  __syncthreads();
#pragma unroll
  for (int i = 0; i < 4; i++)
    WT[(long)(n0 + ty + i * 8) * K + (k0 + tx)] = (_Float16)tile[tx][ty + i * 8];
}

// ---------------- plain rows: f32 -> f16 cast (fallback path only) -----------
__global__ __launch_bounds__(256) void cast_f16(const float* __restrict__ in,
                                                _Float16* __restrict__ out, long n) {
  long i = ((long)blockIdx.x * 256 + threadIdx.x) * 4;
  if (i < n) {
    float4 v = *(const float4*)(in + i);
    typedef _Float16 f16x4 __attribute__((ext_vector_type(4)));
    f16x4 o = {(_Float16)v.x, (_Float16)v.y, (_Float16)v.z, (_Float16)v.w};
    *(f16x4*)(out + i) = o;
  }
}

// ---------------- exact per-row top-k corruption, 1 wave per row -------------
__global__ __launch_bounds__(256) void topk_corrupt(
    const float* __restrict__ noise, const float* __restrict__ x,
    const float* __restrict__ u, const float* __restrict__ mmin,
    const float* __restrict__ mmax, const int* __restrict__ kptr,
    _Float16* __restrict__ dplain, _Float16* __restrict__ dcorr,
    int xrow0, int nrows) {
  int lane = threadIdx.x & 63;
  int r = (blockIdx.x << 2) + (threadIdx.x >> 6);
  if (r >= nrows) return;
  long row = (long)xrow0 + r;
  long rb = row * 512 + lane * 8;
  float4 n0 = *(const float4*)(noise + rb);
  float4 n1 = *(const float4*)(noise + rb + 4);
  unsigned v[8] = {__float_as_uint(n0.x), __float_as_uint(n0.y),
                   __float_as_uint(n0.z), __float_as_uint(n0.w),
                   __float_as_uint(n1.x), __float_as_uint(n1.y),
                   __float_as_uint(n1.z), __float_as_uint(n1.w)};
  int kk = *kptr;
  unsigned T = 0;
  for (int bit = 30; bit >= 0; --bit) {
    unsigned Tp = T | (1u << bit);
    int c = 0;
#pragma unroll
    for (int j = 0; j < 8; j++) c += (int)__popcll(__ballot(v[j] >= Tp));
    if (c >= kk) T = Tp;
  }
  int cgt = 0;
  unsigned long long eqb[8];
#pragma unroll
  for (int j = 0; j < 8; j++) {
    cgt += (int)__popcll(__ballot(v[j] > T));
    eqb[j] = __ballot(v[j] == T);
  }
  int need = kk - cgt;
  unsigned long long below = (1ull << lane) - 1ull;
  int rank_base = 0;
#pragma unroll
  for (int j = 0; j < 8; j++) rank_base += (int)__popcll(eqb[j] & below);

  float4 x0 = *(const float4*)(x + rb);
  float4 x1 = *(const float4*)(x + rb + 4);
  float4 u0 = *(const float4*)(u + rb);
  float4 u1 = *(const float4*)(u + rb + 4);
  int col = lane * 8;
  float4 mn0 = *(const float4*)(mmin + col);
  float4 mn1 = *(const float4*)(mmin + col + 4);
  float4 mx0 = *(const float4*)(mmax + col);
  float4 mx1 = *(const float4*)(mmax + col + 4);
  float xs[8] = {x0.x, x0.y, x0.z, x0.w, x1.x, x1.y, x1.z, x1.w};
  float us[8] = {u0.x, u0.y, u0.z, u0.w, u1.x, u1.y, u1.z, u1.w};
  float mns[8] = {mn0.x, mn0.y, mn0.z, mn0.w, mn1.x, mn1.y, mn1.z, mn1.w};
  float mxs[8] = {mx0.x, mx0.y, mx0.z, mx0.w, mx1.x, mx1.y, mx1.z, mx1.w};

  f16x8 po, co;
  int loc = 0;
#pragma unroll
  for (int j = 0; j < 8; j++) {
    bool eq = (v[j] == T);
    int rank = rank_base + loc;
    bool m = (v[j] > T) || (eq && (rank < need));
    loc += eq ? 1 : 0;
    float rv = mns[j] + us[j] * (mxs[j] - mns[j]);
    float cv = m ? rv : xs[j];
    po[j] = (_Float16)xs[j];
    co[j] = (_Float16)cv;
  }
  long ob = (long)r * 512 + lane * 8;
  if (dplain) *(f16x8*)(dplain + ob) = po;
  *(f16x8*)(dcorr + ob) = co;
}

// ---------------- f16 GEMM: 256x256 tile, BK=32, triple-buffered pipeline ----
// A: MxK row-major f16 (M mult of 256). BT: NxK row-major f16 (N=1024).
// 512 thr = 8 waves (2 Mx4 N). LDS 96 KiB (3 buffers). Counted vmcnt(4),
// one bare s_barrier per K-tile, XOR swizzle chunk^=(row>>1)&3 both sides.
template <bool RELU, bool OUTF32>
__global__ __launch_bounds__(512, 2) void gemm256(const _Float16* __restrict__ A,
                                                  const _Float16* __restrict__ BT,
                                                  const float* __restrict__ bias,
                                                  void* __restrict__ Cout, int K) {
  const int N = 1024;
  __shared__ _Float16 SA[3][256 * 32];
  __shared__ _Float16 SB[3][256 * 32];
  int tid = threadIdx.x;
  int lane = tid & 63, wave = tid >> 6;
  int wr = wave >> 2, wc = wave & 3;            // 2 x 4 waves
  int logical = xcd_swz(blockIdx.x, gridDim.x);
  long arow0 = (long)(logical >> 2) * 256;      // col-fast: 4 col-blocks share A panel
  int bcol0 = (logical & 3) * 256;

  // staging: thread covers LDS f16 [tid*8, tid*8+8) (round0) and +4096 (round1)
  // linear LDS pos (row r, chunk cl) receives global chunk cl ^ ((r>>1)&3)
  int sr = tid >> 2;                                        // 0..127
  int csrc = (((tid & 3) ^ ((tid >> 3) & 3)) * 8);          // pre-swizzled src chunk
  const _Float16* gA0 = A + (arow0 + sr) * (long)K + csrc;
  const _Float16* gA1 = A + (arow0 + 128 + sr) * (long)K + csrc;
  const _Float16* gB0 = BT + (long)(bcol0 + sr) * K + csrc;
  const _Float16* gB1 = BT + (long)(bcol0 + 128 + sr) * K + csrc;
  int lo = tid * 8;

  // fragment reads: row = <frag>*16 + lr, chunk = lane>>4, swizzle (lr>>1)&3
  int lr = lane & 15;
  int cp = (((lane >> 4) ^ ((lr >> 1) & 3)) * 8);

  f32x4 acc[8][4] = {};
  int NT = K / 32;

#define STAGE(b, kt)                          \
  do {                                        \
    gload16(gA0 + (kt), &SA[b][lo]);          \
    gload16(gA1 + (kt), &SA[b][4096 + lo]);   \
    gload16(gB0 + (kt), &SB[b][lo]);          \
    gload16(gB1 + (kt), &SB[b][4096 + lo]);   \
  } while (0)

  STAGE(0, 0);
  STAGE(1, 32);
  asm volatile("s_waitcnt vmcnt(4)" ::: "memory");  // tile 0 landed (all waves')
  __builtin_amdgcn_s_barrier();
  asm volatile("" ::: "memory");

  for (int t = 0; t < NT; ++t) {
    int b = t % 3;
    if (t + 2 < NT) STAGE((t + 2) % 3, (t + 2) * 32);  // buffer freed at end of t-1
    const _Float16* sa = &SA[b][0];
    const _Float16* sb = &SB[b][0];
    f16x8 bf[4], af[4];
#pragma unroll
    for (int n = 0; n < 4; n++)
      bf[n] = *(const f16x8*)&sb[(wc * 64 + n * 16 + lr) * 32 + cp];
#pragma unroll
    for (int m = 0; m < 4; m++)
      af[m] = *(const f16x8*)&sa[(wr * 128 + m * 16 + lr) * 32 + cp];
    __builtin_amdgcn_s_setprio(1);
#pragma unroll
    for (int m = 0; m < 4; m++)
#pragma unroll
      for (int n = 0; n < 4; n++)
        acc[m][n] = __builtin_amdgcn_mfma_f32_16x16x32_f16(af[m], bf[n], acc[m][n], 0, 0, 0);
    __builtin_amdgcn_s_setprio(0);
#pragma unroll
    for (int m = 0; m < 4; m++)
      af[m] = *(const f16x8*)&sa[(wr * 128 + 64 + m * 16 + lr) * 32 + cp];
    __builtin_amdgcn_s_setprio(1);
#pragma unroll
    for (int m = 0; m < 4; m++)
#pragma unroll
      for (int n = 0; n < 4; n++)
        acc[m + 4][n] =
            __builtin_amdgcn_mfma_f32_16x16x32_f16(af[m], bf[n], acc[m + 4][n], 0, 0, 0);
    __builtin_amdgcn_s_setprio(0);
    if (t + 1 < NT) {
      if (t + 2 < NT) asm volatile("s_waitcnt vmcnt(4)" ::: "memory");  // t+1 landed
      else            asm volatile("s_waitcnt vmcnt(0)" ::: "memory");
      __builtin_amdgcn_s_barrier();
      asm volatile("" ::: "memory");
    }
  }
#undef STAGE

  // epilogue: C/D layout col=lane&15, row=(lane>>4)*4+reg
  int r0 = (lane >> 4) * 4;
  float bv[4];
#pragma unroll
  for (int n = 0; n < 4; n++) bv[n] = bias[bcol0 + wc * 64 + n * 16 + lr];
#pragma unroll
  for (int m = 0; m < 8; m++) {
    long rowb = arow0 + wr * 128 + m * 16 + r0;
#pragma unroll
    for (int n = 0; n < 4; n++) {
      int col = bcol0 + wc * 64 + n * 16 + lr;
#pragma unroll
      for (int r = 0; r < 4; r++) {
        float v = acc[m][n][r] + bv[n];
        if (RELU) v = fmaxf(v, 0.f);
        if (OUTF32) ((float*)Cout)[(rowb + r) * N + col] = v;
        else ((_Float16*)Cout)[(rowb + r) * N + col] = (_Float16)v;
      }
    }
  }
}

extern "C" void kernel_launch(void* const* d_in, const int* in_sizes, int n_in,
                              void* d_out, int out_size, void* d_ws, size_t ws_size,
                              hipStream_t stream) {
  const float* x    = (const float*)d_in[0];
  const float* rn   = (const float*)d_in[1];
  const float* ur   = (const float*)d_in[2];
  const float* mmin = (const float*)d_in[3];
  const float* mmax = (const float*)d_in[4];
  const float* W[6]  = {(const float*)d_in[5],  (const float*)d_in[7],  (const float*)d_in[9],
                        (const float*)d_in[11], (const float*)d_in[13], (const float*)d_in[15]};
  const float* Bi[6] = {(const float*)d_in[6],  (const float*)d_in[8],  (const float*)d_in[10],
                        (const float*)d_in[12], (const float*)d_in[14], (const float*)d_in[16]};
  const int* kptr = (const int*)d_in[17];
  float* out = (float*)d_out;

  const long B = 16384;
  const int E = 1024;
  const int Ks[6] = {512, 1024, 1024, 1024, 1024, 1024};

  // ws layout: [wT0..wT5][both_chunk][h0][h1]
  char* ws = (char*)d_ws;
  _Float16* wT[6];
  size_t off = 0;
  for (int i = 0; i < 6; i++) { wT[i] = (_Float16*)(ws + off); off += (size_t)Ks[i] * E * 2; }
  size_t rem = (ws_size > off) ? ws_size - off : 0;
  long R = 32768;
  while (R > 256 && (size_t)R * 5120 > rem) R >>= 1;   // both(1024R)+2*h(4096R) bytes

  _Float16* bothc = (_Float16*)(ws + off);
  _Float16* h0 = bothc + R * 512;
  _Float16* h1 = h0 + R * 1024;

  // one-time (per call) weight transposes
  for (int i = 0; i < 6; i++) {
    dim3 g(E / 32, Ks[i] / 32), b(32, 8);
    transpose_w<<<g, b, 0, stream>>>(W[i], wT[i], Ks[i]);
  }

  for (long r0 = 0; r0 < 2 * B; r0 += R) {
    // ---- build rows [r0, r0+R) of `both` in f16 ----
    if (R == 2 * B) {
      topk_corrupt<<<dim3((unsigned)(B / 4)), dim3(256), 0, stream>>>(
          rn, x, ur, mmin, mmax, kptr, bothc, bothc + B * 512, 0, (int)B);
    } else {
      long plainEnd = (r0 < B) ? ((r0 + R < B) ? (r0 + R) : B) : r0;
      long p1 = plainEnd - r0;
      if (p1 > 0) {
        long n = p1 * 512;
        long blocks = (n / 4 + 255) / 256;
        cast_f16<<<dim3((unsigned)blocks), dim3(256), 0, stream>>>(x + r0 * 512, bothc, n);
      }
      long c0 = (r0 > B) ? r0 : B;
      long p2 = (r0 + R) - c0;
      if (p2 > 0) {
        topk_corrupt<<<dim3((unsigned)((p2 + 3) / 4)), dim3(256), 0, stream>>>(
            rn, x, ur, mmin, mmax, kptr, (_Float16*)nullptr,
            bothc + (c0 - r0) * 512, (int)(c0 - B), (int)p2);
      }
    }
    // ---- 6-layer MLP on this chunk ----
    dim3 gg((unsigned)((R / 256) * 4)), gb(512);
    gemm256<true,  false><<<gg, gb, 0, stream>>>(bothc, wT[0], Bi[0], (void*)h0, 512);
    gemm256<true,  false><<<gg, gb, 0, stream>>>(h0,    wT[1], Bi[1], (void*)h1, 1024);
    gemm256<true,  false><<<gg, gb, 0, stream>>>(h1,    wT[2], Bi[2], (void*)h0, 1024);
    gemm256<false, false><<<gg, gb, 0, stream>>>(h0,    wT[3], Bi[3], (void*)h1, 1024);
    gemm256<true,  false><<<gg, gb, 0, stream>>>(h1,    wT[4], Bi[4], (void*)h0, 1024);
    gemm256<false, true ><<<gg, gb, 0, stream>>>(h0,    wT[5], Bi[5],
                                                 (void*)(out + r0 * 1024), 1024);
  }
}

// Round 4
// 431.649 us; speedup vs baseline: 1.6610x; 1.2984x over previous
//
#include <hip/hip_runtime.h>

typedef _Float16 f16x8 __attribute__((ext_vector_type(8)));
typedef float f32x4 __attribute__((ext_vector_type(4)));

__device__ __forceinline__ void gload16(const void* g, void* l) {
  __builtin_amdgcn_global_load_lds(
      (const __attribute__((address_space(1))) void*)g,
      (__attribute__((address_space(3))) void*)l, 16, 0, 0);
}

__device__ __forceinline__ void barfence() {
  asm volatile("" ::: "memory");
  __builtin_amdgcn_s_barrier();
  asm volatile("" ::: "memory");
}

// m204 bijective XCD swizzle
__device__ __forceinline__ int xcd_swz(int orig, int nwg) {
  int q = nwg >> 3, r = nwg & 7;
  int x = orig & 7, loc = orig >> 3;
  int base = (x < r) ? x * (q + 1) : r * (q + 1) + (x - r) * q;
  return base + loc;
}

// ---------------- weight transpose + cast: W (KxN f32) -> WT (NxK f16) -------
__global__ __launch_bounds__(256) void transpose_w(const float* __restrict__ W,
                                                   _Float16* __restrict__ WT, int K) {
  const int N = 1024;
  __shared__ float tile[32][33];
  int tx = threadIdx.x, ty = threadIdx.y;  // (32,8)
  int n0 = blockIdx.x * 32, k0 = blockIdx.y * 32;
#pragma unroll
  for (int i = 0; i < 4; i++)
    tile[ty + i * 8][tx] = W[(long)(k0 + ty + i * 8) * N + (n0 + tx)];
  __syncthreads();
#pragma unroll
  for (int i = 0; i < 4; i++)
    WT[(long)(n0 + ty + i * 8) * K + (k0 + tx)] = (_Float16)tile[tx][ty + i * 8];
}

// ---------------- plain rows: f32 -> f16 cast (fallback path only) -----------
__global__ __launch_bounds__(256) void cast_f16(const float* __restrict__ in,
                                                _Float16* __restrict__ out, long n) {
  long i = ((long)blockIdx.x * 256 + threadIdx.x) * 4;
  if (i < n) {
    float4 v = *(const float4*)(in + i);
    typedef _Float16 f16x4 __attribute__((ext_vector_type(4)));
    f16x4 o = {(_Float16)v.x, (_Float16)v.y, (_Float16)v.z, (_Float16)v.w};
    *(f16x4*)(out + i) = o;
  }
}

// ---------------- exact per-row top-k corruption, 1 wave per row -------------
__global__ __launch_bounds__(256) void topk_corrupt(
    const float* __restrict__ noise, const float* __restrict__ x,
    const float* __restrict__ u, const float* __restrict__ mmin,
    const float* __restrict__ mmax, const int* __restrict__ kptr,
    _Float16* __restrict__ dplain, _Float16* __restrict__ dcorr,
    int xrow0, int nrows) {
  int lane = threadIdx.x & 63;
  int r = (blockIdx.x << 2) + (threadIdx.x >> 6);
  if (r >= nrows) return;
  long row = (long)xrow0 + r;
  long rb = row * 512 + lane * 8;
  float4 n0 = *(const float4*)(noise + rb);
  float4 n1 = *(const float4*)(noise + rb + 4);
  unsigned v[8] = {__float_as_uint(n0.x), __float_as_uint(n0.y),
                   __float_as_uint(n0.z), __float_as_uint(n0.w),
                   __float_as_uint(n1.x), __float_as_uint(n1.y),
                   __float_as_uint(n1.z), __float_as_uint(n1.w)};
  int kk = *kptr;
  unsigned T = 0;
  for (int bit = 30; bit >= 0; --bit) {
    unsigned Tp = T | (1u << bit);
    int c = 0;
#pragma unroll
    for (int j = 0; j < 8; j++) c += (int)__popcll(__ballot(v[j] >= Tp));
    if (c >= kk) T = Tp;
  }
  int cgt = 0;
  unsigned long long eqb[8];
#pragma unroll
  for (int j = 0; j < 8; j++) {
    cgt += (int)__popcll(__ballot(v[j] > T));
    eqb[j] = __ballot(v[j] == T);
  }
  int need = kk - cgt;
  unsigned long long below = (1ull << lane) - 1ull;
  int rank_base = 0;
#pragma unroll
  for (int j = 0; j < 8; j++) rank_base += (int)__popcll(eqb[j] & below);

  float4 x0 = *(const float4*)(x + rb);
  float4 x1 = *(const float4*)(x + rb + 4);
  float4 u0 = *(const float4*)(u + rb);
  float4 u1 = *(const float4*)(u + rb + 4);
  int col = lane * 8;
  float4 mn0 = *(const float4*)(mmin + col);
  float4 mn1 = *(const float4*)(mmin + col + 4);
  float4 mx0 = *(const float4*)(mmax + col);
  float4 mx1 = *(const float4*)(mmax + col + 4);
  float xs[8] = {x0.x, x0.y, x0.z, x0.w, x1.x, x1.y, x1.z, x1.w};
  float us[8] = {u0.x, u0.y, u0.z, u0.w, u1.x, u1.y, u1.z, u1.w};
  float mns[8] = {mn0.x, mn0.y, mn0.z, mn0.w, mn1.x, mn1.y, mn1.z, mn1.w};
  float mxs[8] = {mx0.x, mx0.y, mx0.z, mx0.w, mx1.x, mx1.y, mx1.z, mx1.w};

  f16x8 po, co;
  int loc = 0;
#pragma unroll
  for (int j = 0; j < 8; j++) {
    bool eq = (v[j] == T);
    int rank = rank_base + loc;
    bool m = (v[j] > T) || (eq && (rank < need));
    loc += eq ? 1 : 0;
    float rv = mns[j] + us[j] * (mxs[j] - mns[j]);
    float cv = m ? rv : xs[j];
    po[j] = (_Float16)xs[j];
    co[j] = (_Float16)cv;
  }
  long ob = (long)r * 512 + lane * 8;
  if (dplain) *(f16x8*)(dplain + ob) = po;
  *(f16x8*)(dcorr + ob) = co;
}

// ---------------- f16 GEMM: 256x256 tile, BK=64, 8-phase (m201 port) ---------
// A: MxK row-major f16 (M mult of 256). BT: NxK row-major f16 (N=1024).
// 8 waves (2Mx4N), wave-tile 128x64 crossing halves: quadrant (mq,nq) picks
// A-half mq / B-half nq. LDS 2buf x 4 units x 16KB = 128 KiB.
// Per tile: 4 phases {reads | stage | bar | 16 MFMA | bar}; one vmcnt(4)/tile.
// Swizzle: chunk ^= (row&7) on 128B rows, both sides.
template <bool RELU, bool OUTF32>
__global__ __launch_bounds__(512, 2) void gemm8p(const _Float16* __restrict__ A,
                                                 const _Float16* __restrict__ BT,
                                                 const float* __restrict__ bias,
                                                 void* __restrict__ Cout, int K) {
  const int N = 1024;
  __shared__ _Float16 S[2][4][8192];  // [buf][A0,A1,B0,B1][128 rows x 64 f16]
  int tid = threadIdx.x;
  int lane = tid & 63, wave = tid >> 6;
  int wr = wave >> 2, wc = wave & 3;  // 2 x 4
  int logical = xcd_swz(blockIdx.x, gridDim.x);
  long arow0 = (long)(logical >> 2) * 256;
  int bcol0 = (logical & 3) * 256;

  // staging: unit = 128 rows x 8 chunks(16B). thread covers (row=j*64+tid>>3,
  // chunk cl=tid&7) for j=0,1; source global chunk = cl ^ (row&7).
  int srow = tid >> 3;                       // 0..63
  int scg = (tid & 7) ^ (srow & 7);          // pre-swizzled source chunk
  const _Float16* gA[2][2];
  const _Float16* gB[2][2];
#pragma unroll
  for (int h = 0; h < 2; h++)
#pragma unroll
    for (int j = 0; j < 2; j++) {
      gA[h][j] = A + (arow0 + h * 128 + j * 64 + srow) * (long)K + scg * 8;
      gB[h][j] = BT + (long)(bcol0 + h * 128 + j * 64 + srow) * K + scg * 8;
    }
  int lo = tid * 8;  // f16 offset of this thread's 16B slot (load j adds 4096)

#define STG_A(BUF, H, T)                                   \
  do {                                                     \
    gload16(gA[H][0] + (T) * 64, &S[BUF][H][lo]);          \
    gload16(gA[H][1] + (T) * 64, &S[BUF][H][4096 + lo]);   \
  } while (0)
#define STG_B(BUF, H, T)                                      \
  do {                                                        \
    gload16(gB[H][0] + (T) * 64, &S[BUF][2 + H][lo]);         \
    gload16(gB[H][1] + (T) * 64, &S[BUF][2 + H][4096 + lo]);  \
  } while (0)

  // fragment read offsets: row r in half, chunk (kk*4+g)^(lr&7)
  int lr = lane & 15, g = lane >> 4, e = lr & 7;
  int cs0 = ((0 * 4 + g) ^ e) * 8;
  int cs1 = ((1 * 4 + g) ^ e) * 8;
  int aoff[4], boff[2];
#pragma unroll
  for (int mf = 0; mf < 4; mf++) aoff[mf] = (wr * 64 + mf * 16 + lr) * 64;
#pragma unroll
  for (int nf = 0; nf < 2; nf++) boff[nf] = (wc * 32 + nf * 16 + lr) * 64;

  f16x8 af[4][2];     // current A quadrant (mq), [mfrag][kk]
  f16x8 bf[2][2][2];  // both B halves live: [nq][nfrag][kk]
  f32x4 acc[2][2][4][2] = {};  // [mq][nq][mfrag][nfrag]

#define LDA(BUF, MQ)                                                 \
  do {                                                               \
    _Pragma("unroll") for (int mf = 0; mf < 4; mf++) {               \
      af[mf][0] = *(const f16x8*)&S[BUF][MQ][aoff[mf] + cs0];        \
      af[mf][1] = *(const f16x8*)&S[BUF][MQ][aoff[mf] + cs1];        \
    }                                                                \
  } while (0)
#define LDB(BUF, NQ)                                                 \
  do {                                                               \
    _Pragma("unroll") for (int nf = 0; nf < 2; nf++) {               \
      bf[NQ][nf][0] = *(const f16x8*)&S[BUF][2 + NQ][boff[nf] + cs0];\
      bf[NQ][nf][1] = *(const f16x8*)&S[BUF][2 + NQ][boff[nf] + cs1];\
    }                                                                \
  } while (0)
#define MFMA_Q(MQ, NQ)                                               \
  do {                                                               \
    __builtin_amdgcn_s_setprio(1);                                   \
    _Pragma("unroll") for (int mf = 0; mf < 4; mf++)                 \
    _Pragma("unroll") for (int nf = 0; nf < 2; nf++)                 \
    _Pragma("unroll") for (int kk = 0; kk < 2; kk++)                 \
      acc[MQ][NQ][mf][nf] = __builtin_amdgcn_mfma_f32_16x16x32_f16(  \
          af[mf][kk], bf[NQ][nf][kk], acc[MQ][NQ][mf][nf], 0, 0, 0); \
    __builtin_amdgcn_s_setprio(0);                                   \
  } while (0)

  int NT = K / 64;
  // prologue: tile0 all 4 units, then A0,B0 of tile1; wait so tile0 resident
  STG_A(0, 0, 0); STG_B(0, 0, 0); STG_A(0, 1, 0); STG_B(0, 1, 0);
  if (NT > 1) {
    STG_A(1, 0, 1); STG_B(1, 0, 1);
    asm volatile("s_waitcnt vmcnt(4)" ::: "memory");
  } else {
    asm volatile("s_waitcnt vmcnt(0)" ::: "memory");
  }
  barfence();

  for (int t = 0; t < NT; ++t) {
    int buf = t & 1, nbuf = buf ^ 1;
    // ---- ph1 (mq0,nq0): 12 reads; stage A1,B1 of t+1 into nbuf
    LDA(buf, 0);
    LDB(buf, 0);
    if (t + 1 < NT) { STG_A(nbuf, 1, t + 1); STG_B(nbuf, 1, t + 1); }
    barfence();
    MFMA_Q(0, 0);
    barfence();
    // ---- ph2 (mq0,nq1): 4 reads
    LDB(buf, 1);
    barfence();
    MFMA_Q(0, 1);
    barfence();
    // ---- ph3 (mq1,nq0): 8 reads; stage A0 of t+2 into buf
    LDA(buf, 1);
    if (t + 2 < NT) STG_A(buf, 0, t + 2);
    barfence();
    MFMA_Q(1, 0);
    barfence();
    // ---- ph4 (mq1,nq1): stage B0 of t+2; counted vmcnt once per tile
    if (t + 2 < NT) STG_B(buf, 0, t + 2);
    if (t + 1 < NT) {
      if (t + 2 < NT) asm volatile("s_waitcnt vmcnt(4)" ::: "memory");
      else            asm volatile("s_waitcnt vmcnt(0)" ::: "memory");
    }
    barfence();
    MFMA_Q(1, 1);
    if (t + 1 < NT) barfence();
  }
#undef STG_A
#undef STG_B
#undef LDA
#undef LDB
#undef MFMA_Q

  // epilogue: C/D layout col=lane&15, row=(lane>>4)*4+reg
  int r0 = (lane >> 4) * 4;
  float bv[2][2];
#pragma unroll
  for (int nq = 0; nq < 2; nq++)
#pragma unroll
    for (int nf = 0; nf < 2; nf++)
      bv[nq][nf] = bias[bcol0 + nq * 128 + wc * 32 + nf * 16 + lr];
#pragma unroll
  for (int mq = 0; mq < 2; mq++)
#pragma unroll
    for (int mf = 0; mf < 4; mf++) {
      long rowb = arow0 + mq * 128 + wr * 64 + mf * 16 + r0;
#pragma unroll
      for (int nq = 0; nq < 2; nq++)
#pragma unroll
        for (int nf = 0; nf < 2; nf++) {
          int col = bcol0 + nq * 128 + wc * 32 + nf * 16 + lr;
#pragma unroll
          for (int rr = 0; rr < 4; rr++) {
            float v = acc[mq][nq][mf][nf][rr] + bv[nq][nf];
            if (RELU) v = fmaxf(v, 0.f);
            if (OUTF32) ((float*)Cout)[(rowb + rr) * N + col] = v;
            else ((_Float16*)Cout)[(rowb + rr) * N + col] = (_Float16)v;
          }
        }
    }
}

extern "C" void kernel_launch(void* const* d_in, const int* in_sizes, int n_in,
                              void* d_out, int out_size, void* d_ws, size_t ws_size,
                              hipStream_t stream) {
  const float* x    = (const float*)d_in[0];
  const float* rn   = (const float*)d_in[1];
  const float* ur   = (const float*)d_in[2];
  const float* mmin = (const float*)d_in[3];
  const float* mmax = (const float*)d_in[4];
  const float* W[6]  = {(const float*)d_in[5],  (const float*)d_in[7],  (const float*)d_in[9],
                        (const float*)d_in[11], (const float*)d_in[13], (const float*)d_in[15]};
  const float* Bi[6] = {(const float*)d_in[6],  (const float*)d_in[8],  (const float*)d_in[10],
                        (const float*)d_in[12], (const float*)d_in[14], (const float*)d_in[16]};
  const int* kptr = (const int*)d_in[17];
  float* out = (float*)d_out;

  const long B = 16384;
  const int E = 1024;
  const int Ks[6] = {512, 1024, 1024, 1024, 1024, 1024};

  // ws layout: [wT0..wT5][both_chunk][h0][h1]
  char* ws = (char*)d_ws;
  _Float16* wT[6];
  size_t off = 0;
  for (int i = 0; i < 6; i++) { wT[i] = (_Float16*)(ws + off); off += (size_t)Ks[i] * E * 2; }
  size_t rem = (ws_size > off) ? ws_size - off : 0;
  long R = 32768;
  while (R > 256 && (size_t)R * 5120 > rem) R >>= 1;   // both(1024R)+2*h(4096R) bytes

  _Float16* bothc = (_Float16*)(ws + off);
  _Float16* h0 = bothc + R * 512;
  _Float16* h1 = h0 + R * 1024;

  // one-time (per call) weight transposes
  for (int i = 0; i < 6; i++) {
    dim3 g(E / 32, Ks[i] / 32), b(32, 8);
    transpose_w<<<g, b, 0, stream>>>(W[i], wT[i], Ks[i]);
  }

  for (long r0 = 0; r0 < 2 * B; r0 += R) {
    // ---- build rows [r0, r0+R) of `both` in f16 ----
    if (R == 2 * B) {
      topk_corrupt<<<dim3((unsigned)(B / 4)), dim3(256), 0, stream>>>(
          rn, x, ur, mmin, mmax, kptr, bothc, bothc + B * 512, 0, (int)B);
    } else {
      long plainEnd = (r0 < B) ? ((r0 + R < B) ? (r0 + R) : B) : r0;
      long p1 = plainEnd - r0;
      if (p1 > 0) {
        long n = p1 * 512;
        long blocks = (n / 4 + 255) / 256;
        cast_f16<<<dim3((unsigned)blocks), dim3(256), 0, stream>>>(x + r0 * 512, bothc, n);
      }
      long c0 = (r0 > B) ? r0 : B;
      long p2 = (r0 + R) - c0;
      if (p2 > 0) {
        topk_corrupt<<<dim3((unsigned)((p2 + 3) / 4)), dim3(256), 0, stream>>>(
            rn, x, ur, mmin, mmax, kptr, (_Float16*)nullptr,
            bothc + (c0 - r0) * 512, (int)(c0 - B), (int)p2);
      }
    }
    // ---- 6-layer MLP on this chunk ----
    dim3 gg((unsigned)((R / 256) * 4)), gb(512);
    gemm8p<true,  false><<<gg, gb, 0, stream>>>(bothc, wT[0], Bi[0], (void*)h0, 512);
    gemm8p<true,  false><<<gg, gb, 0, stream>>>(h0,    wT[1], Bi[1], (void*)h1, 1024);
    gemm8p<true,  false><<<gg, gb, 0, stream>>>(h1,    wT[2], Bi[2], (void*)h0, 1024);
    gemm8p<false, false><<<gg, gb, 0, stream>>>(h0,    wT[3], Bi[3], (void*)h1, 1024);
    gemm8p<true,  false><<<gg, gb, 0, stream>>>(h1,    wT[4], Bi[4], (void*)h0, 1024);
    gemm8p<false, true ><<<gg, gb, 0, stream>>>(h0,    wT[5], Bi[5],
                                                 (void*)(out + r0 * 1024), 1024);
  }
}

// Round 5
// 413.533 us; speedup vs baseline: 1.7338x; 1.0438x over previous
//
#include <hip/hip_runtime.h>

typedef _Float16 f16x8 __attribute__((ext_vector_type(8)));
typedef float f32x4 __attribute__((ext_vector_type(4)));

__device__ __forceinline__ void gload16(const void* g, void* l) {
  __builtin_amdgcn_global_load_lds(
      (const __attribute__((address_space(1))) void*)g,
      (__attribute__((address_space(3))) void*)l, 16, 0, 0);
}

__device__ __forceinline__ void barfence() {
  asm volatile("" ::: "memory");
  __builtin_amdgcn_s_barrier();
  asm volatile("" ::: "memory");
}

// m204 bijective XCD swizzle
__device__ __forceinline__ int xcd_swz(int orig, int nwg) {
  int q = nwg >> 3, r = nwg & 7;
  int x = orig & 7, loc = orig >> 3;
  int base = (x < r) ? x * (q + 1) : r * (q + 1) + (x - r) * q;
  return base + loc;
}

// ---------------- weight transpose + cast: W (KxN f32) -> WT (NxK f16) -------
__global__ __launch_bounds__(256) void transpose_w(const float* __restrict__ W,
                                                   _Float16* __restrict__ WT, int K) {
  const int N = 1024;
  __shared__ float tile[32][33];
  int tx = threadIdx.x, ty = threadIdx.y;  // (32,8)
  int n0 = blockIdx.x * 32, k0 = blockIdx.y * 32;
#pragma unroll
  for (int i = 0; i < 4; i++)
    tile[ty + i * 8][tx] = W[(long)(k0 + ty + i * 8) * N + (n0 + tx)];
  __syncthreads();
#pragma unroll
  for (int i = 0; i < 4; i++)
    WT[(long)(n0 + ty + i * 8) * K + (k0 + tx)] = (_Float16)tile[tx][ty + i * 8];
}

// ---------------- plain rows: f32 -> f16 cast (fallback path only) -----------
__global__ __launch_bounds__(256) void cast_f16(const float* __restrict__ in,
                                                _Float16* __restrict__ out, long n) {
  long i = ((long)blockIdx.x * 256 + threadIdx.x) * 4;
  if (i < n) {
    float4 v = *(const float4*)(in + i);
    typedef _Float16 f16x4 __attribute__((ext_vector_type(4)));
    f16x4 o = {(_Float16)v.x, (_Float16)v.y, (_Float16)v.z, (_Float16)v.w};
    *(f16x4*)(out + i) = o;
  }
}

// ---------------- exact per-row top-k corruption, 1 wave per row -------------
__global__ __launch_bounds__(256) void topk_corrupt(
    const float* __restrict__ noise, const float* __restrict__ x,
    const float* __restrict__ u, const float* __restrict__ mmin,
    const float* __restrict__ mmax, const int* __restrict__ kptr,
    _Float16* __restrict__ dplain, _Float16* __restrict__ dcorr,
    int xrow0, int nrows) {
  int lane = threadIdx.x & 63;
  int r = (blockIdx.x << 2) + (threadIdx.x >> 6);
  if (r >= nrows) return;
  long row = (long)xrow0 + r;
  long rb = row * 512 + lane * 8;
  float4 n0 = *(const float4*)(noise + rb);
  float4 n1 = *(const float4*)(noise + rb + 4);
  unsigned v[8] = {__float_as_uint(n0.x), __float_as_uint(n0.y),
                   __float_as_uint(n0.z), __float_as_uint(n0.w),
                   __float_as_uint(n1.x), __float_as_uint(n1.y),
                   __float_as_uint(n1.z), __float_as_uint(n1.w)};
  int kk = *kptr;
  unsigned T = 0;
  for (int bit = 30; bit >= 0; --bit) {
    unsigned Tp = T | (1u << bit);
    int c = 0;
#pragma unroll
    for (int j = 0; j < 8; j++) c += (int)__popcll(__ballot(v[j] >= Tp));
    if (c >= kk) T = Tp;
  }
  int cgt = 0;
  unsigned long long eqb[8];
#pragma unroll
  for (int j = 0; j < 8; j++) {
    cgt += (int)__popcll(__ballot(v[j] > T));
    eqb[j] = __ballot(v[j] == T);
  }
  int need = kk - cgt;
  unsigned long long below = (1ull << lane) - 1ull;
  int rank_base = 0;
#pragma unroll
  for (int j = 0; j < 8; j++) rank_base += (int)__popcll(eqb[j] & below);

  float4 x0 = *(const float4*)(x + rb);
  float4 x1 = *(const float4*)(x + rb + 4);
  float4 u0 = *(const float4*)(u + rb);
  float4 u1 = *(const float4*)(u + rb + 4);
  int col = lane * 8;
  float4 mn0 = *(const float4*)(mmin + col);
  float4 mn1 = *(const float4*)(mmin + col + 4);
  float4 mx0 = *(const float4*)(mmax + col);
  float4 mx1 = *(const float4*)(mmax + col + 4);
  float xs[8] = {x0.x, x0.y, x0.z, x0.w, x1.x, x1.y, x1.z, x1.w};
  float us[8] = {u0.x, u0.y, u0.z, u0.w, u1.x, u1.y, u1.z, u1.w};
  float mns[8] = {mn0.x, mn0.y, mn0.z, mn0.w, mn1.x, mn1.y, mn1.z, mn1.w};
  float mxs[8] = {mx0.x, mx0.y, mx0.z, mx0.w, mx1.x, mx1.y, mx1.z, mx1.w};

  f16x8 po, co;
  int loc = 0;
#pragma unroll
  for (int j = 0; j < 8; j++) {
    bool eq = (v[j] == T);
    int rank = rank_base + loc;
    bool m = (v[j] > T) || (eq && (rank < need));
    loc += eq ? 1 : 0;
    float rv = mns[j] + us[j] * (mxs[j] - mns[j]);
    float cv = m ? rv : xs[j];
    po[j] = (_Float16)xs[j];
    co[j] = (_Float16)cv;
  }
  long ob = (long)r * 512 + lane * 8;
  if (dplain) *(f16x8*)(dplain + ob) = po;
  *(f16x8*)(dcorr + ob) = co;
}

// ---------------- f16 GEMM: 256x256 tile, BK=64, 4 fused phases/tile ---------
// A: MxK row-major f16 (M mult of 256). BT: NxK row-major f16 (N=1024).
// 8 waves (2Mx4N), wave-tile 128x64 crossing halves. LDS 2buf x 4 units = 128K.
// Each phase = ONE region {ds_reads ; stage ; 16 MFMA} ; s_barrier — compiler
// interleaves reads/stage with MFMA via partial lgkmcnt. 4 barriers/tile,
// one counted vmcnt(4)/tile. Swizzle chunk ^= (row&7), both sides.
// Race proof (single barrier suffices): every region's ds_reads are consumed
// (lgkm-drained) by the same phase's MFMA; each staged LDS unit is re-written
// >=1 barrier after its last consuming phase:
//   A1,B1(t+1)->nbuf @ph1(t); last consumed ph3(t-1)  => 2 bars
//   A0(t+2)->buf    @ph2(t); consumed ph1(t)          => 1 bar
//   B0(t+2)->buf    @ph3(t); consumed ph1(t)          => 2 bars
// vmcnt: 12 outstanding at ph4 -> vmcnt(4) retires all 8 of tile t+1.
template <bool RELU, bool OUTF32>
__global__ __launch_bounds__(512, 2) void gemm8p(const _Float16* __restrict__ A,
                                                 const _Float16* __restrict__ BT,
                                                 const float* __restrict__ bias,
                                                 void* __restrict__ Cout, int K) {
  const int N = 1024;
  __shared__ _Float16 S[2][4][8192];  // [buf][A0,A1,B0,B1][128 rows x 64 f16]
  int tid = threadIdx.x;
  int lane = tid & 63, wave = tid >> 6;
  int wr = wave >> 2, wc = wave & 3;  // 2 x 4
  int logical = xcd_swz(blockIdx.x, gridDim.x);
  long arow0 = (long)(logical >> 2) * 256;
  int bcol0 = (logical & 3) * 256;

  // staging: unit = 128 rows x 8 chunks(16B). thread covers (row=j*64+tid>>3,
  // chunk cl=tid&7) for j=0,1; source global chunk = cl ^ (row&7).
  int srow = tid >> 3;                       // 0..63
  int scg = (tid & 7) ^ (srow & 7);          // pre-swizzled source chunk
  const _Float16* gA[2][2];
  const _Float16* gB[2][2];
#pragma unroll
  for (int h = 0; h < 2; h++)
#pragma unroll
    for (int j = 0; j < 2; j++) {
      gA[h][j] = A + (arow0 + h * 128 + j * 64 + srow) * (long)K + scg * 8;
      gB[h][j] = BT + (long)(bcol0 + h * 128 + j * 64 + srow) * K + scg * 8;
    }
  int lo = tid * 8;  // f16 offset of this thread's 16B slot (load j adds 4096)

#define STG_A(BUF, H, T)                                   \
  do {                                                     \
    gload16(gA[H][0] + (T) * 64, &S[BUF][H][lo]);          \
    gload16(gA[H][1] + (T) * 64, &S[BUF][H][4096 + lo]);   \
  } while (0)
#define STG_B(BUF, H, T)                                      \
  do {                                                        \
    gload16(gB[H][0] + (T) * 64, &S[BUF][2 + H][lo]);         \
    gload16(gB[H][1] + (T) * 64, &S[BUF][2 + H][4096 + lo]);  \
  } while (0)

  // fragment read offsets: row r in half, chunk (kk*4+g)^(lr&7)
  int lr = lane & 15, g = lane >> 4, e = lr & 7;
  int cs0 = ((0 * 4 + g) ^ e) * 8;
  int cs1 = ((1 * 4 + g) ^ e) * 8;
  int aoff[4], boff[2];
#pragma unroll
  for (int mf = 0; mf < 4; mf++) aoff[mf] = (wr * 64 + mf * 16 + lr) * 64;
#pragma unroll
  for (int nf = 0; nf < 2; nf++) boff[nf] = (wc * 32 + nf * 16 + lr) * 64;

  f16x8 af[4][2];     // current A quadrant (mq), [mfrag][kk]
  f16x8 bf[2][2][2];  // both B halves live: [nq][nfrag][kk]
  f32x4 acc[2][2][4][2] = {};  // [mq][nq][mfrag][nfrag]

#define LDA(BUF, MQ)                                                 \
  do {                                                               \
    _Pragma("unroll") for (int mf = 0; mf < 4; mf++) {               \
      af[mf][0] = *(const f16x8*)&S[BUF][MQ][aoff[mf] + cs0];        \
      af[mf][1] = *(const f16x8*)&S[BUF][MQ][aoff[mf] + cs1];        \
    }                                                                \
  } while (0)
#define LDB(BUF, NQ)                                                 \
  do {                                                               \
    _Pragma("unroll") for (int nf = 0; nf < 2; nf++) {               \
      bf[NQ][nf][0] = *(const f16x8*)&S[BUF][2 + NQ][boff[nf] + cs0];\
      bf[NQ][nf][1] = *(const f16x8*)&S[BUF][2 + NQ][boff[nf] + cs1];\
    }                                                                \
  } while (0)
#define MFMA_Q(MQ, NQ)                                               \
  do {                                                               \
    __builtin_amdgcn_s_setprio(1);                                   \
    _Pragma("unroll") for (int mf = 0; mf < 4; mf++)                 \
    _Pragma("unroll") for (int nf = 0; nf < 2; nf++)                 \
    _Pragma("unroll") for (int kk = 0; kk < 2; kk++)                 \
      acc[MQ][NQ][mf][nf] = __builtin_amdgcn_mfma_f32_16x16x32_f16(  \
          af[mf][kk], bf[NQ][nf][kk], acc[MQ][NQ][mf][nf], 0, 0, 0); \
    __builtin_amdgcn_s_setprio(0);                                   \
  } while (0)

  int NT = K / 64;
  // prologue: tile0 all 4 units -> buf0; A0,B0 of tile1 -> buf1
  STG_A(0, 0, 0); STG_B(0, 0, 0); STG_A(0, 1, 0); STG_B(0, 1, 0);
  if (NT > 1) {
    STG_A(1, 0, 1); STG_B(1, 0, 1);
    asm volatile("s_waitcnt vmcnt(4)" ::: "memory");
  } else {
    asm volatile("s_waitcnt vmcnt(0)" ::: "memory");
  }
  barfence();

  for (int t = 0; t < NT; ++t) {
    int buf = t & 1, nbuf = buf ^ 1;
    // ---- ph1: reads (0,0) ops; stage A1,B1 of t+1; MFMA(0,0)
    LDB(buf, 0);
    LDA(buf, 0);
    if (t + 1 < NT) { STG_A(nbuf, 1, t + 1); STG_B(nbuf, 1, t + 1); }
    MFMA_Q(0, 0);
    barfence();
    // ---- ph2: read B half1; stage A0 of t+2; MFMA(0,1)
    LDB(buf, 1);
    if (t + 2 < NT) STG_A(buf, 0, t + 2);
    MFMA_Q(0, 1);
    barfence();
    // ---- ph3: read A half1 (overwrites af); stage B0 of t+2; MFMA(1,0)
    LDA(buf, 1);
    if (t + 2 < NT) STG_B(buf, 0, t + 2);
    MFMA_Q(1, 0);
    barfence();
    // ---- ph4: counted vmcnt (t+1 fully resident after barrier); MFMA(1,1)
    if (t + 1 < NT) {
      if (t + 2 < NT) asm volatile("s_waitcnt vmcnt(4)" ::: "memory");
      else            asm volatile("s_waitcnt vmcnt(0)" ::: "memory");
    }
    MFMA_Q(1, 1);
    if (t + 1 < NT) barfence();
  }
#undef STG_A
#undef STG_B
#undef LDA
#undef LDB
#undef MFMA_Q

  // epilogue: C/D layout col=lane&15, row=(lane>>4)*4+reg
  int r0 = (lane >> 4) * 4;
  float bv[2][2];
#pragma unroll
  for (int nq = 0; nq < 2; nq++)
#pragma unroll
    for (int nf = 0; nf < 2; nf++)
      bv[nq][nf] = bias[bcol0 + nq * 128 + wc * 32 + nf * 16 + lr];
#pragma unroll
  for (int mq = 0; mq < 2; mq++)
#pragma unroll
    for (int mf = 0; mf < 4; mf++) {
      long rowb = arow0 + mq * 128 + wr * 64 + mf * 16 + r0;
#pragma unroll
      for (int nq = 0; nq < 2; nq++)
#pragma unroll
        for (int nf = 0; nf < 2; nf++) {
          int col = bcol0 + nq * 128 + wc * 32 + nf * 16 + lr;
#pragma unroll
          for (int rr = 0; rr < 4; rr++) {
            float v = acc[mq][nq][mf][nf][rr] + bv[nq][nf];
            if (RELU) v = fmaxf(v, 0.f);
            if (OUTF32) ((float*)Cout)[(rowb + rr) * N + col] = v;
            else ((_Float16*)Cout)[(rowb + rr) * N + col] = (_Float16)v;
          }
        }
    }
}

extern "C" void kernel_launch(void* const* d_in, const int* in_sizes, int n_in,
                              void* d_out, int out_size, void* d_ws, size_t ws_size,
                              hipStream_t stream) {
  const float* x    = (const float*)d_in[0];
  const float* rn   = (const float*)d_in[1];
  const float* ur   = (const float*)d_in[2];
  const float* mmin = (const float*)d_in[3];
  const float* mmax = (const float*)d_in[4];
  const float* W[6]  = {(const float*)d_in[5],  (const float*)d_in[7],  (const float*)d_in[9],
                        (const float*)d_in[11], (const float*)d_in[13], (const float*)d_in[15]};
  const float* Bi[6] = {(const float*)d_in[6],  (const float*)d_in[8],  (const float*)d_in[10],
                        (const float*)d_in[12], (const float*)d_in[14], (const float*)d_in[16]};
  const int* kptr = (const int*)d_in[17];
  float* out = (float*)d_out;

  const long B = 16384;
  const int E = 1024;
  const int Ks[6] = {512, 1024, 1024, 1024, 1024, 1024};

  // ws layout: [wT0..wT5][both_chunk][h0][h1]
  char* ws = (char*)d_ws;
  _Float16* wT[6];
  size_t off = 0;
  for (int i = 0; i < 6; i++) { wT[i] = (_Float16*)(ws + off); off += (size_t)Ks[i] * E * 2; }
  size_t rem = (ws_size > off) ? ws_size - off : 0;
  long R = 32768;
  while (R > 256 && (size_t)R * 5120 > rem) R >>= 1;   // both(1024R)+2*h(4096R) bytes

  _Float16* bothc = (_Float16*)(ws + off);
  _Float16* h0 = bothc + R * 512;
  _Float16* h1 = h0 + R * 1024;

  // one-time (per call) weight transposes
  for (int i = 0; i < 6; i++) {
    dim3 g(E / 32, Ks[i] / 32), b(32, 8);
    transpose_w<<<g, b, 0, stream>>>(W[i], wT[i], Ks[i]);
  }

  for (long r0 = 0; r0 < 2 * B; r0 += R) {
    // ---- build rows [r0, r0+R) of `both` in f16 ----
    if (R == 2 * B) {
      topk_corrupt<<<dim3((unsigned)(B / 4)), dim3(256), 0, stream>>>(
          rn, x, ur, mmin, mmax, kptr, bothc, bothc + B * 512, 0, (int)B);
    } else {
      long plainEnd = (r0 < B) ? ((r0 + R < B) ? (r0 + R) : B) : r0;
      long p1 = plainEnd - r0;
      if (p1 > 0) {
        long n = p1 * 512;
        long blocks = (n / 4 + 255) / 256;
        cast_f16<<<dim3((unsigned)blocks), dim3(256), 0, stream>>>(x + r0 * 512, bothc, n);
      }
      long c0 = (r0 > B) ? r0 : B;
      long p2 = (r0 + R) - c0;
      if (p2 > 0) {
        topk_corrupt<<<dim3((unsigned)((p2 + 3) / 4)), dim3(256), 0, stream>>>(
            rn, x, ur, mmin, mmax, kptr, (_Float16*)nullptr,
            bothc + (c0 - r0) * 512, (int)(c0 - B), (int)p2);
      }
    }
    // ---- 6-layer MLP on this chunk ----
    dim3 gg((unsigned)((R / 256) * 4)), gb(512);
    gemm8p<true,  false><<<gg, gb, 0, stream>>>(bothc, wT[0], Bi[0], (void*)h0, 512);
    gemm8p<true,  false><<<gg, gb, 0, stream>>>(h0,    wT[1], Bi[1], (void*)h1, 1024);
    gemm8p<true,  false><<<gg, gb, 0, stream>>>(h1,    wT[2], Bi[2], (void*)h0, 1024);
    gemm8p<false, false><<<gg, gb, 0, stream>>>(h0,    wT[3], Bi[3], (void*)h1, 1024);
    gemm8p<true,  false><<<gg, gb, 0, stream>>>(h1,    wT[4], Bi[4], (void*)h0, 1024);
    gemm8p<false, true ><<<gg, gb, 0, stream>>>(h0,    wT[5], Bi[5],
                                                 (void*)(out + r0 * 1024), 1024);
  }
}